// Round 9
// baseline (379.776 us; speedup 1.0000x reference)
//
#include <hip/hip_runtime.h>
#include <hip/hip_bf16.h>

#define N_TOK 8192
#define DIM   2048
#define NEXP  8
#define BM    288          // sum ceil(c_e/288) == 32 for c_e in [865,1152] -> 256 tiles
#define BN    256
#define BK    32
#define NT    (DIM / BK)   // 64 K-steps
#define NBLK  256          // persistent: exactly 1 block per CU

#define A_BYTES  (BM * BK * 2)            // 18432
#define B_BYTES  (BN * BK * 2)            // 16384
#define RING     (A_BYTES + B_BYTES)      // 34816
#define DYN_LDS  (4 * RING)               // 139264 (ring-4)

typedef __attribute__((ext_vector_type(8))) short  short8;
typedef __attribute__((ext_vector_type(4))) float  f32x4;
typedef __attribute__((ext_vector_type(4))) unsigned int u32x4;

static __device__ __forceinline__ unsigned int pack_bf2(float a, float b) {
  union { __hip_bfloat16 h; unsigned short u; } ca, cb;
  ca.h = __float2bfloat16(a);
  cb.h = __float2bfloat16(b);
  return ((unsigned int)cb.u << 16) | (unsigned int)ca.u;
}

static __device__ __forceinline__ void gload16(const unsigned short* g, void* l) {
  __builtin_amdgcn_global_load_lds(
      (const __attribute__((address_space(1))) unsigned int*)(const void*)g,
      (__attribute__((address_space(3))) unsigned int*)l, 16, 0, 0);
}

static __device__ __forceinline__ double dot8d(const float4& x0, const float4& x1,
                                               const float4& w0, const float4& w1) {
  double a = 0.0;
  a = fma((double)x0.x, (double)w0.x, a);
  a = fma((double)x0.y, (double)w0.y, a);
  a = fma((double)x0.z, (double)w0.z, a);
  a = fma((double)x0.w, (double)w0.w, a);
  a = fma((double)x1.x, (double)w1.x, a);
  a = fma((double)x1.y, (double)w1.y, a);
  a = fma((double)x1.z, (double)w1.z, a);
  a = fma((double)x1.w, (double)w1.w, a);
  return a;
}

// ---------------- W -> bf16 convert (unchanged, round 8) ----------------
__global__ __launch_bounds__(256) void convw_kernel(
    const float* __restrict__ w, unsigned short* __restrict__ wbuf)
{
  const size_t c0 = (size_t)blockIdx.x * 1024 + threadIdx.x;
  float4 f[8];
#pragma unroll
  for (int i = 0; i < 4; i++) {
    const float4* s = reinterpret_cast<const float4*>(w + (c0 + i * 256) * 8);
    f[2 * i]     = s[0];
    f[2 * i + 1] = s[1];
  }
#pragma unroll
  for (int i = 0; i < 4; i++) {
    u32x4 pk;
    pk[0] = pack_bf2(f[2*i].x,   f[2*i].y);   pk[1] = pack_bf2(f[2*i].z,   f[2*i].w);
    pk[2] = pack_bf2(f[2*i+1].x, f[2*i+1].y); pk[3] = pack_bf2(f[2*i+1].z, f[2*i+1].w);
    *reinterpret_cast<u32x4*>(wbuf + (c0 + i * 256) * 8) = pk;
  }
}

// ---------------- router (unchanged, round 8) ----------------
__global__ __launch_bounds__(256, 3) void router_kernel(
    const float* __restrict__ x, const float* __restrict__ rw,
    const float* __restrict__ rb, int* __restrict__ eid,
    float* __restrict__ gate, unsigned short* __restrict__ xb)
{
  const int t    = threadIdx.x;
  const int tok0 = blockIdx.x * 4;

  float4 w0[NEXP], w1[NEXP];
#pragma unroll
  for (int e = 0; e < NEXP; e++) {
    const float4* wr = reinterpret_cast<const float4*>(rw + (size_t)e * DIM);
    w0[e] = wr[2 * t];
    w1[e] = wr[2 * t + 1];
  }
  float4 xv0[4], xv1[4];
#pragma unroll
  for (int k = 0; k < 4; k++) {
    const float4* xr = reinterpret_cast<const float4*>(x + (size_t)(tok0 + k) * DIM);
    xv0[k] = xr[2 * t];
    xv1[k] = xr[2 * t + 1];
  }
#pragma unroll
  for (int k = 0; k < 4; k++) {
    u32x4 pk;
    pk[0] = pack_bf2(xv0[k].x, xv0[k].y); pk[1] = pack_bf2(xv0[k].z, xv0[k].w);
    pk[2] = pack_bf2(xv1[k].x, xv1[k].y); pk[3] = pack_bf2(xv1[k].z, xv1[k].w);
    *reinterpret_cast<u32x4*>(xb + (size_t)(tok0 + k) * DIM + t * 8) = pk;
  }

  __shared__ double red[4][4][NEXP];
  const int lane = t & 63, wv = t >> 6;
#pragma unroll
  for (int k = 0; k < 4; k++) {
    double s[NEXP];
#pragma unroll
    for (int e = 0; e < NEXP; e++) s[e] = dot8d(xv0[k], xv1[k], w0[e], w1[e]);
#pragma unroll
    for (int e = 0; e < NEXP; e++) {
      double v = s[e];
#pragma unroll
      for (int off = 32; off > 0; off >>= 1) v += __shfl_xor(v, off, 64);
      if (lane == 0) red[wv][k][e] = v;
    }
  }
  __syncthreads();
  if (t < 4) {
    double lg[NEXP];
    double lmax = -1e300; int best = 0;
#pragma unroll
    for (int e = 0; e < NEXP; e++) {
      lg[e] = red[0][t][e] + red[1][t][e] + red[2][t][e] + red[3][t][e] + (double)rb[e];
      if (lg[e] > lmax) { lmax = lg[e]; best = e; }   // strict > == first-occurrence argmax
    }
    float den = 0.f;
#pragma unroll
    for (int e = 0; e < NEXP; e++) den += expf((float)(lg[e] - lmax));
    eid[tok0 + t]  = best;
    gate[tok0 + t] = 1.0f / den;
  }
}

// ---------------- histo + permute (unchanged, round 8) ----------------
__global__ __launch_bounds__(1024) void histo_perm(
    const int* __restrict__ eid, int* __restrict__ counts, int* __restrict__ perm)
{
  __shared__ int hist[NEXP], baseS[NEXP], fillS[NEXP];
  const int t = threadIdx.x;
  if (t < NEXP) { hist[t] = 0; fillS[t] = 0; }
  __syncthreads();
  int my[8];
#pragma unroll
  for (int i = 0; i < 8; i++) {
    my[i] = eid[t + i * 1024];
    atomicAdd(&hist[my[i]], 1);
  }
  __syncthreads();
  if (t == 0) {
    int b = 0;
#pragma unroll
    for (int e = 0; e < NEXP; e++) { counts[e] = hist[e]; baseS[e] = b; b += hist[e]; }
  }
  __syncthreads();
#pragma unroll
  for (int i = 0; i < 8; i++) {
    int pos = baseS[my[i]] + atomicAdd(&fillS[my[i]], 1);
    perm[pos] = t + i * 1024;
  }
}

// ------- grouped GEMM: ring-4, counted vmcnt, reg-dbuf frags, read/MFMA overlap -------
// Step i: vmcnt(own loads of slot i+1) -> s_barrier["memory"] (publish slot i+1, free
// slot i-1) -> gload slot i+3 -> ds_read slot i+1 (next regs) -> MFMA(i) on cur regs.
// Reads drain in the LDS pipe WHILE the matrix pipe runs MFMA(i) -> pipes overlap.
#define VMW(N) asm volatile("s_waitcnt vmcnt(" #N ")" ::: "memory")
#define BARM() asm volatile("s_barrier" ::: "memory")

#define GLOADS(GS)                                                          \
  do {                                                                      \
    gload16(aSrc[0], (GS) + aDst[0]);                                       \
    gload16(aSrc[1], (GS) + aDst[1]);                                       \
    if (nA5) gload16(aSrc[2], (GS) + aDst[2]);                              \
    gload16(bSrc[0], (GS) + bDst[0]);                                       \
    gload16(bSrc[1], (GS) + bDst[1]);                                       \
    aSrc[0] += BK; aSrc[1] += BK; aSrc[2] += BK;                            \
    bSrc[0] += BK; bSrc[1] += BK;                                           \
  } while (0)

#define DS_READS(RS, RAF, RBF)                                              \
  do {                                                                      \
    _Pragma("unroll")                                                       \
    for (int n = 0; n < 4; n++) RBF[n] = *(const short8*)((RS) + bOff + n * 1024); \
    _Pragma("unroll")                                                       \
    for (int m = 0; m < 9; m++) RAF[m] = *(const short8*)((RS) + aOff + m * 1024); \
  } while (0)

#define MFMA36(MAF, MBF)                                                    \
  do {                                                                      \
    __builtin_amdgcn_sched_barrier(0);                                      \
    __builtin_amdgcn_s_setprio(1);                                          \
    _Pragma("unroll")                                                       \
    for (int m = 0; m < 9; m++)                                             \
      _Pragma("unroll")                                                     \
      for (int n = 0; n < 4; n++)                                           \
        acc[m][n] = __builtin_amdgcn_mfma_f32_16x16x32_bf16(MAF[m], MBF[n], \
                                                            acc[m][n], 0, 0, 0); \
    __builtin_amdgcn_s_setprio(0);                                          \
  } while (0)

#define STEP(RS, RAF, RBF, MAF, MBF, GS)                                    \
  do {                                                                      \
    if (nA5) VMW(5); else VMW(4);                                           \
    BARM();                                                                 \
    GLOADS(GS);                                                             \
    DS_READS(RS, RAF, RBF);                                                 \
    MFMA36(MAF, MBF);                                                       \
  } while (0)

__global__ __launch_bounds__(512, 2) void moe_gemm(
    const unsigned short* __restrict__ xb, const unsigned short* __restrict__ wb,
    const float* __restrict__ eb, const float* __restrict__ gate,
    const int* __restrict__ perm, const int* __restrict__ counts,
    float* __restrict__ out)
{
  extern __shared__ char smem[];     // 4 ring slots of {A 18432 B | B 16384 B}
  __shared__ int   aRowS[BM];
  __shared__ float gateS[BM];

  const int tid  = threadIdx.x;
  const int lane = tid & 63, wid = tid >> 6;

  int ttot = 0;
#pragma unroll
  for (int j = 0; j < NEXP; j++) ttot += (counts[j] + BM - 1) / BM;
  ttot *= 8;

  // ---- staging geometry (16-row chunks of 64B rows; 1KB per wave-load) ----
  const int nA5 = (wid < 2);           // waves 0-1 carry a 3rd A chunk
  int aR0[3], bR0[2];
  aR0[0] = (wid * 2) * 16;
  aR0[1] = (wid * 2 + 1) * 16;
  aR0[2] = nA5 ? ((16 + wid) * 16) : aR0[0];
  bR0[0] = (wid * 2) * 16;
  bR0[1] = (wid * 2 + 1) * 16;
  int aDst[3], bDst[2];
#pragma unroll
  for (int i = 0; i < 3; i++) aDst[i] = aR0[i] * 64;
#pragma unroll
  for (int i = 0; i < 2; i++) bDst[i] = A_BYTES + bR0[i] * 64;
  const int lrow = lane >> 2;                          // row within 16-row chunk
  const int cblk = (lane & 3) ^ ((lane >> 3) & 3);     // pre-swizzled src block (involution)

  // ---- MFMA fragment addressing (2M x 4N waves; per-wave 144x64 output) ----
  const int l15 = lane & 15;
  const int wr = wid >> 2, wc = wid & 3;
  const int sw   = (((lane >> 4) ^ ((l15 >> 1) & 3)) * 16);   // read-side swizzle
  const int aOff = (wr * 144 + l15) * 64 + sw;
  const int bOff = A_BYTES + (wc * 64 + l15) * 64 + sw;
  const int rsub = (lane >> 4) * 4;

  char* const s0 = smem;
  char* const s1 = smem + RING;
  char* const s2 = smem + 2 * RING;
  char* const s3 = smem + 3 * RING;

  for (int tt = blockIdx.x; tt < ttot; tt += NBLK) {
    const int bx = tt >> 3, by = tt & 7;

    int e = 0, rowbase = 0, nrows = 0, found = 0;
    {
      int tsum = 0, bsum = 0;
#pragma unroll
      for (int j = 0; j < NEXP; j++) {
        int cj = counts[j];
        int te = (cj + BM - 1) / BM;
        if (!found && bx < tsum + te) {
          int loc = bx - tsum;
          e = j;
          rowbase = bsum + loc * BM;
          int rem = cj - loc * BM;
          nrows = rem < BM ? rem : BM;
          found = 1;
        }
        tsum += te; bsum += cj;
      }
    }

    __syncthreads();   // full drain; prior tile done with aRowS/gateS and LDS
    if (tid < BM) {
      int idx = tid < nrows ? tid : (nrows - 1);
      int tok = perm[rowbase + idx];
      aRowS[tid] = tok;
      gateS[tid] = gate[tok];
    }
    __syncthreads();

    const unsigned short* wB = wb + (size_t)e * DIM * DIM;
    const unsigned short* aSrc[3];
    const unsigned short* bSrc[2];
#pragma unroll
    for (int i = 0; i < 3; i++)
      aSrc[i] = xb + (size_t)aRowS[aR0[i] + lrow] * DIM + cblk * 8;
#pragma unroll
    for (int i = 0; i < 2; i++)
      bSrc[i] = wB + (size_t)(by * BN + bR0[i] + lrow) * DIM + cblk * 8;

    // ---- prologue: stage steps 0..2 into slots 0..2; publish slot 0; read step 0 ----
    GLOADS(s0); GLOADS(s1); GLOADS(s2);
    if (nA5) VMW(10); else VMW(8);      // own slot-0 loads done
    BARM();                              // publish slot 0 group-wide

    f32x4 acc[9][4] = {};
    short8 afA[9], bfA[4], afB[9], bfB[4];
    DS_READS(s0, afA, bfA);              // step 0 -> set A (drains under loop head)

    // ---- steady state: steps 0..59 (15 macro-iters of 4) ----
#pragma unroll 1
    for (int k = 0; k < 15; ++k) {
      STEP(s1, afB, bfB, afA, bfA, s3);  // i=4k+0: read s1->B, gload s3, MFMA A
      STEP(s2, afA, bfA, afB, bfB, s0);  // i=4k+1
      STEP(s3, afB, bfB, afA, bfA, s1);  // i=4k+2
      STEP(s0, afA, bfA, afB, bfB, s2);  // i=4k+3
    }
    // ---- epilogue: steps 60..63 ----
    STEP(s1, afB, bfB, afA, bfA, s3);    // i=60: gload step 63 -> slot 3
    {                                    // i=61: no gload
      if (nA5) VMW(5); else VMW(4);
      BARM();
      DS_READS(s2, afA, bfA);
      MFMA36(afB, bfB);
    }
    {                                    // i=62: drain all, read step 63
      VMW(0);
      BARM();
      DS_READS(s3, afB, bfB);
      MFMA36(afA, bfA);
    }
    MFMA36(afB, bfB);                    // i=63

    // ---- epilogue: +bias, *gate, scatter by token ----
    const int cb = by * BN + wc * 64;
    const float* ebE = eb + (size_t)e * DIM;
    float bias[4];
#pragma unroll
    for (int n = 0; n < 4; n++) bias[n] = ebE[cb + n * 16 + l15];
#pragma unroll
    for (int m = 0; m < 9; m++) {
      int r0 = wr * 144 + m * 16 + rsub;
#pragma unroll
      for (int rg = 0; rg < 4; rg++) {
        int r = r0 + rg;
        if (r < nrows) {
          float g = gateS[r];
          float* orow = out + (size_t)aRowS[r] * DIM + cb;
#pragma unroll
          for (int n = 0; n < 4; n++)
            orow[n * 16 + l15] = (acc[m][n][rg] + bias[n]) * g;
        }
      }
    }
    VMW(0);   // drain stores so next tile's counted vmcnt isn't polluted
  }
}

extern "C" void kernel_launch(void* const* d_in, const int* in_sizes, int n_in,
                              void* d_out, int out_size, void* d_ws, size_t ws_size,
                              hipStream_t stream)
{
  const float* x  = (const float*)d_in[0];
  const float* ew = (const float*)d_in[1];
  const float* eb = (const float*)d_in[2];
  const float* rw = (const float*)d_in[3];
  const float* rb = (const float*)d_in[4];
  float* out = (float*)d_out;

  char* ws = (char*)d_ws;
  int*   eid    = (int*)(ws);                  // 8192 ints
  float* gate   = (float*)(ws + 32 * 1024);    // 8192 floats
  int*   counts = (int*)(ws + 64 * 1024);      // [0..7]
  int*   perm   = (int*)(ws + 128 * 1024);     // 8192 ints
  unsigned short* xbuf = (unsigned short*)(ws + 192 * 1024);                               // 32 MB
  unsigned short* wbuf = (unsigned short*)(ws + 192 * 1024 + ((size_t)N_TOK * DIM * 2));   // 64 MB

  hipFuncSetAttribute(reinterpret_cast<const void*>(moe_gemm),
                      hipFuncAttributeMaxDynamicSharedMemorySize, DYN_LDS);

  hipMemsetAsync(out + (size_t)N_TOK * DIM, 0, sizeof(float), stream);      // loss = 0
  convw_kernel<<<4096, 256, 0, stream>>>(ew, wbuf);
  router_kernel<<<N_TOK / 4, 256, 0, stream>>>(x, rw, rb, eid, gate, xbuf);
  histo_perm<<<1, 1024, 0, stream>>>(eid, counts, perm);
  moe_gemm<<<NBLK, 512, DYN_LDS, stream>>>(xbuf, wbuf, eb, gate, perm, counts, out);
}

// Round 10
// 175.073 us; speedup vs baseline: 2.1692x; 2.1692x over previous
//
#include <hip/hip_runtime.h>
#include <hip/hip_bf16.h>

#define N_TOK 8192
#define DIM   2048
#define NEXP  8
#define BM    288          // sum ceil(c_e/288) == 32 for c_e in [865,1152] -> 256 tiles
#define BN    256
#define BK    32
#define NT    (DIM / BK)   // 64 K-steps
#define NBLK  256          // persistent: exactly 1 block per CU

#define A_BYTES  (BM * BK * 2)            // 18432
#define B_BYTES  (BN * BK * 2)            // 16384
#define RING     (A_BYTES + B_BYTES)      // 34816
#define DYN_LDS  (4 * RING)               // 139264 (ring-4)

typedef __attribute__((ext_vector_type(8))) short  short8;
typedef __attribute__((ext_vector_type(4))) float  f32x4;
typedef __attribute__((ext_vector_type(4))) unsigned int u32x4;

static __device__ __forceinline__ unsigned int pack_bf2(float a, float b) {
  union { __hip_bfloat16 h; unsigned short u; } ca, cb;
  ca.h = __float2bfloat16(a);
  cb.h = __float2bfloat16(b);
  return ((unsigned int)cb.u << 16) | (unsigned int)ca.u;
}

static __device__ __forceinline__ void gload16(const unsigned short* g, void* l) {
  __builtin_amdgcn_global_load_lds(
      (const __attribute__((address_space(1))) unsigned int*)(const void*)g,
      (__attribute__((address_space(3))) unsigned int*)l, 16, 0, 0);
}

static __device__ __forceinline__ double dot8d(const float4& x0, const float4& x1,
                                               const float4& w0, const float4& w1) {
  double a = 0.0;
  a = fma((double)x0.x, (double)w0.x, a);
  a = fma((double)x0.y, (double)w0.y, a);
  a = fma((double)x0.z, (double)w0.z, a);
  a = fma((double)x0.w, (double)w0.w, a);
  a = fma((double)x1.x, (double)w1.x, a);
  a = fma((double)x1.y, (double)w1.y, a);
  a = fma((double)x1.z, (double)w1.z, a);
  a = fma((double)x1.w, (double)w1.w, a);
  return a;
}

// ---------------- W -> bf16 convert (unchanged, round 8) ----------------
__global__ __launch_bounds__(256) void convw_kernel(
    const float* __restrict__ w, unsigned short* __restrict__ wbuf)
{
  const size_t c0 = (size_t)blockIdx.x * 1024 + threadIdx.x;
  float4 f[8];
#pragma unroll
  for (int i = 0; i < 4; i++) {
    const float4* s = reinterpret_cast<const float4*>(w + (c0 + i * 256) * 8);
    f[2 * i]     = s[0];
    f[2 * i + 1] = s[1];
  }
#pragma unroll
  for (int i = 0; i < 4; i++) {
    u32x4 pk;
    pk[0] = pack_bf2(f[2*i].x,   f[2*i].y);   pk[1] = pack_bf2(f[2*i].z,   f[2*i].w);
    pk[2] = pack_bf2(f[2*i+1].x, f[2*i+1].y); pk[3] = pack_bf2(f[2*i+1].z, f[2*i+1].w);
    *reinterpret_cast<u32x4*>(wbuf + (c0 + i * 256) * 8) = pk;
  }
}

// ---------------- router (unchanged, round 8) ----------------
__global__ __launch_bounds__(256, 3) void router_kernel(
    const float* __restrict__ x, const float* __restrict__ rw,
    const float* __restrict__ rb, int* __restrict__ eid,
    float* __restrict__ gate, unsigned short* __restrict__ xb)
{
  const int t    = threadIdx.x;
  const int tok0 = blockIdx.x * 4;

  float4 w0[NEXP], w1[NEXP];
#pragma unroll
  for (int e = 0; e < NEXP; e++) {
    const float4* wr = reinterpret_cast<const float4*>(rw + (size_t)e * DIM);
    w0[e] = wr[2 * t];
    w1[e] = wr[2 * t + 1];
  }
  float4 xv0[4], xv1[4];
#pragma unroll
  for (int k = 0; k < 4; k++) {
    const float4* xr = reinterpret_cast<const float4*>(x + (size_t)(tok0 + k) * DIM);
    xv0[k] = xr[2 * t];
    xv1[k] = xr[2 * t + 1];
  }
#pragma unroll
  for (int k = 0; k < 4; k++) {
    u32x4 pk;
    pk[0] = pack_bf2(xv0[k].x, xv0[k].y); pk[1] = pack_bf2(xv0[k].z, xv0[k].w);
    pk[2] = pack_bf2(xv1[k].x, xv1[k].y); pk[3] = pack_bf2(xv1[k].z, xv1[k].w);
    *reinterpret_cast<u32x4*>(xb + (size_t)(tok0 + k) * DIM + t * 8) = pk;
  }

  __shared__ double red[4][4][NEXP];
  const int lane = t & 63, wv = t >> 6;
#pragma unroll
  for (int k = 0; k < 4; k++) {
    double s[NEXP];
#pragma unroll
    for (int e = 0; e < NEXP; e++) s[e] = dot8d(xv0[k], xv1[k], w0[e], w1[e]);
#pragma unroll
    for (int e = 0; e < NEXP; e++) {
      double v = s[e];
#pragma unroll
      for (int off = 32; off > 0; off >>= 1) v += __shfl_xor(v, off, 64);
      if (lane == 0) red[wv][k][e] = v;
    }
  }
  __syncthreads();
  if (t < 4) {
    double lg[NEXP];
    double lmax = -1e300; int best = 0;
#pragma unroll
    for (int e = 0; e < NEXP; e++) {
      lg[e] = red[0][t][e] + red[1][t][e] + red[2][t][e] + red[3][t][e] + (double)rb[e];
      if (lg[e] > lmax) { lmax = lg[e]; best = e; }   // strict > == first-occurrence argmax
    }
    float den = 0.f;
#pragma unroll
    for (int e = 0; e < NEXP; e++) den += expf((float)(lg[e] - lmax));
    eid[tok0 + t]  = best;
    gate[tok0 + t] = 1.0f / den;
  }
}

// ---------------- histo + permute (unchanged, round 8) ----------------
__global__ __launch_bounds__(1024) void histo_perm(
    const int* __restrict__ eid, int* __restrict__ counts, int* __restrict__ perm)
{
  __shared__ int hist[NEXP], baseS[NEXP], fillS[NEXP];
  const int t = threadIdx.x;
  if (t < NEXP) { hist[t] = 0; fillS[t] = 0; }
  __syncthreads();
  int my[8];
#pragma unroll
  for (int i = 0; i < 8; i++) {
    my[i] = eid[t + i * 1024];
    atomicAdd(&hist[my[i]], 1);
  }
  __syncthreads();
  if (t == 0) {
    int b = 0;
#pragma unroll
    for (int e = 0; e < NEXP; e++) { counts[e] = hist[e]; baseS[e] = b; b += hist[e]; }
  }
  __syncthreads();
#pragma unroll
  for (int i = 0; i < 8; i++) {
    int pos = baseS[my[i]] + atomicAdd(&fillS[my[i]], 1);
    perm[pos] = t + i * 1024;
  }
}

// ------- grouped GEMM: ring-4, counted vmcnt (true depth), 3-sub-phase K-step -------
// Per K-step t: VMW(own slot-t loads) -> s_barrier (publish slot t, free slot t-1) ->
//   P0 {read bf0-3+af0-2, gload A(t+3), bar+lgkm0, 12 MFMA}
//   P1 {read af3-5,       gload B(t+3), bar+lgkm0, 12 MFMA}
//   P2 {read af6-8,                     bar+lgkm0, 12 MFMA}
// Small read/MFMA chunks = m201 phase discipline (T3); registers = round-8 budget.
#define VMW(N) asm volatile("s_waitcnt vmcnt(" #N ")" ::: "memory")
#define BARM() asm volatile("s_barrier" ::: "memory")
#define PHASE_BAR()                                                         \
  do {                                                                      \
    BARM();                                                                 \
    asm volatile("s_waitcnt lgkmcnt(0)" ::: "memory");                      \
    __builtin_amdgcn_sched_barrier(0);                                      \
  } while (0)

#define MFMA_G(M0)                                                          \
  do {                                                                      \
    __builtin_amdgcn_s_setprio(1);                                          \
    _Pragma("unroll")                                                       \
    for (int m = (M0); m < (M0) + 3; m++)                                   \
      _Pragma("unroll")                                                     \
      for (int n = 0; n < 4; n++)                                           \
        acc[m][n] = __builtin_amdgcn_mfma_f32_16x16x32_bf16(af[m], bf[n],   \
                                                            acc[m][n], 0, 0, 0); \
    __builtin_amdgcn_s_setprio(0);                                          \
  } while (0)

#define GLOADS(GS)                                                          \
  do {                                                                      \
    gload16(aSrc[0], (GS) + aDst[0]);                                       \
    gload16(aSrc[1], (GS) + aDst[1]);                                       \
    if (nA5) gload16(aSrc[2], (GS) + aDst[2]);                              \
    gload16(bSrc[0], (GS) + bDst[0]);                                       \
    gload16(bSrc[1], (GS) + bDst[1]);                                       \
    aSrc[0] += BK; aSrc[1] += BK; aSrc[2] += BK;                            \
    bSrc[0] += BK; bSrc[1] += BK;                                           \
  } while (0)

__global__ __launch_bounds__(512, 2) void moe_gemm(
    const unsigned short* __restrict__ xb, const unsigned short* __restrict__ wb,
    const float* __restrict__ eb, const float* __restrict__ gate,
    const int* __restrict__ perm, const int* __restrict__ counts,
    float* __restrict__ out)
{
  extern __shared__ char smem[];     // 4 ring slots of {A 18432 B | B 16384 B}
  __shared__ int   aRowS[BM];
  __shared__ float gateS[BM];

  const int tid  = threadIdx.x;
  const int lane = tid & 63, wid = tid >> 6;

  int ttot = 0;
#pragma unroll
  for (int j = 0; j < NEXP; j++) ttot += (counts[j] + BM - 1) / BM;
  ttot *= 8;

  // ---- staging geometry (16-row chunks of 64B rows; 1KB per wave-load) ----
  const int nA5 = (wid < 2);           // waves 0-1 carry a 3rd A chunk
  int aR0[3], bR0[2];
  aR0[0] = (wid * 2) * 16;
  aR0[1] = (wid * 2 + 1) * 16;
  aR0[2] = nA5 ? ((16 + wid) * 16) : aR0[0];
  bR0[0] = (wid * 2) * 16;
  bR0[1] = (wid * 2 + 1) * 16;
  int aDst[3], bDst[2];
#pragma unroll
  for (int i = 0; i < 3; i++) aDst[i] = aR0[i] * 64;
#pragma unroll
  for (int i = 0; i < 2; i++) bDst[i] = A_BYTES + bR0[i] * 64;
  const int lrow = lane >> 2;                          // row within 16-row chunk
  const int cblk = (lane & 3) ^ ((lane >> 3) & 3);     // pre-swizzled src block (involution)

  // ---- MFMA fragment addressing (2M x 4N waves; per-wave 144x64 output) ----
  const int l15 = lane & 15;
  const int wr = wid >> 2, wc = wid & 3;
  const int sw   = (((lane >> 4) ^ ((l15 >> 1) & 3)) * 16);   // read-side swizzle
  const int aOff = (wr * 144 + l15) * 64 + sw;
  const int bOff = A_BYTES + (wc * 64 + l15) * 64 + sw;
  const int rsub = (lane >> 4) * 4;

  for (int tt = blockIdx.x; tt < ttot; tt += NBLK) {
    const int bx = tt >> 3, by = tt & 7;

    int e = 0, rowbase = 0, nrows = 0, found = 0;
    {
      int tsum = 0, bsum = 0;
#pragma unroll
      for (int j = 0; j < NEXP; j++) {
        int cj = counts[j];
        int te = (cj + BM - 1) / BM;
        if (!found && bx < tsum + te) {
          int loc = bx - tsum;
          e = j;
          rowbase = bsum + loc * BM;
          int rem = cj - loc * BM;
          nrows = rem < BM ? rem : BM;
          found = 1;
        }
        tsum += te; bsum += cj;
      }
    }

    __syncthreads();   // prior tile fully done with aRowS/gateS and LDS slots
    if (tid < BM) {
      int idx = tid < nrows ? tid : (nrows - 1);
      int tok = perm[rowbase + idx];
      aRowS[tid] = tok;
      gateS[tid] = gate[tok];
    }
    __syncthreads();

    const unsigned short* wB = wb + (size_t)e * DIM * DIM;
    const unsigned short* aSrc[3];
    const unsigned short* bSrc[2];
#pragma unroll
    for (int i = 0; i < 3; i++)
      aSrc[i] = xb + (size_t)aRowS[aR0[i] + lrow] * DIM + cblk * 8;
#pragma unroll
    for (int i = 0; i < 2; i++)
      bSrc[i] = wB + (size_t)(by * BN + bR0[i] + lrow) * DIM + cblk * 8;

    // ---- prologue: stage K-steps 0..2 into ring slots 0..2 ----
    GLOADS(smem);
    GLOADS(smem + RING);
    GLOADS(smem + 2 * RING);

    f32x4 acc[9][4] = {};

#pragma unroll 1
    for (int t = 0; t < NT; ++t) {
      // counted wait on OWN loads of slot t only (true depth: t+1,t+2 stay in flight)
      if (t < NT - 2) {
        if (nA5) VMW(10); else VMW(8);
      } else if (t == NT - 2) {
        if (nA5) VMW(5); else VMW(4);
      } else {
        VMW(0);
      }
      BARM();   // publish slot t group-wide; slot (t-1)&3 now free for overwrite

      const char* cur = smem + (t & 3) * RING;
      char*       nxt = smem + ((t + 3) & 3) * RING;
      const bool  pf  = (t + 3 < NT);
      short8 af[9], bf[4];

      // ---- P0: B frags + first A chunk; issue A-gloads(t+3) ----
#pragma unroll
      for (int n = 0; n < 4; n++) bf[n] = *(const short8*)(cur + bOff + n * 1024);
#pragma unroll
      for (int m = 0; m < 3; m++) af[m] = *(const short8*)(cur + aOff + m * 1024);
      if (pf) {
        gload16(aSrc[0], nxt + aDst[0]);
        gload16(aSrc[1], nxt + aDst[1]);
        if (nA5) gload16(aSrc[2], nxt + aDst[2]);
      }
      PHASE_BAR();
      MFMA_G(0);

      // ---- P1: second A chunk; issue B-gloads(t+3) ----
#pragma unroll
      for (int m = 3; m < 6; m++) af[m] = *(const short8*)(cur + aOff + m * 1024);
      if (pf) {
        gload16(bSrc[0], nxt + bDst[0]);
        gload16(bSrc[1], nxt + bDst[1]);
        aSrc[0] += BK; aSrc[1] += BK; aSrc[2] += BK;
        bSrc[0] += BK; bSrc[1] += BK;
      }
      PHASE_BAR();
      MFMA_G(3);

      // ---- P2: third A chunk ----
#pragma unroll
      for (int m = 6; m < 9; m++) af[m] = *(const short8*)(cur + aOff + m * 1024);
      PHASE_BAR();
      MFMA_G(6);
    }

    // ---- epilogue: +bias, *gate, scatter by token ----
    const int cb = by * BN + wc * 64;
    const float* ebE = eb + (size_t)e * DIM;
    float bias[4];
#pragma unroll
    for (int n = 0; n < 4; n++) bias[n] = ebE[cb + n * 16 + l15];
#pragma unroll
    for (int m = 0; m < 9; m++) {
      int r0 = wr * 144 + m * 16 + rsub;
#pragma unroll
      for (int rg = 0; rg < 4; rg++) {
        int r = r0 + rg;
        if (r < nrows) {
          float g = gateS[r];
          float* orow = out + (size_t)aRowS[r] * DIM + cb;
#pragma unroll
          for (int n = 0; n < 4; n++)
            orow[n * 16 + l15] = (acc[m][n][rg] + bias[n]) * g;
        }
      }
    }
    VMW(0);   // drain stores so next tile's counted vmcnt isn't polluted
  }
}

extern "C" void kernel_launch(void* const* d_in, const int* in_sizes, int n_in,
                              void* d_out, int out_size, void* d_ws, size_t ws_size,
                              hipStream_t stream)
{
  const float* x  = (const float*)d_in[0];
  const float* ew = (const float*)d_in[1];
  const float* eb = (const float*)d_in[2];
  const float* rw = (const float*)d_in[3];
  const float* rb = (const float*)d_in[4];
  float* out = (float*)d_out;

  char* ws = (char*)d_ws;
  int*   eid    = (int*)(ws);                  // 8192 ints
  float* gate   = (float*)(ws + 32 * 1024);    // 8192 floats
  int*   counts = (int*)(ws + 64 * 1024);      // [0..7]
  int*   perm   = (int*)(ws + 128 * 1024);     // 8192 ints
  unsigned short* xbuf = (unsigned short*)(ws + 192 * 1024);                               // 32 MB
  unsigned short* wbuf = (unsigned short*)(ws + 192 * 1024 + ((size_t)N_TOK * DIM * 2));   // 64 MB

  hipFuncSetAttribute(reinterpret_cast<const void*>(moe_gemm),
                      hipFuncAttributeMaxDynamicSharedMemorySize, DYN_LDS);

  hipMemsetAsync(out + (size_t)N_TOK * DIM, 0, sizeof(float), stream);      // loss = 0
  convw_kernel<<<4096, 256, 0, stream>>>(ew, wbuf);
  router_kernel<<<N_TOK / 4, 256, 0, stream>>>(x, rw, rb, eid, gate, xbuf);
  histo_perm<<<1, 1024, 0, stream>>>(eid, counts, perm);
  moe_gemm<<<NBLK, 512, DYN_LDS, stream>>>(xbuf, wbuf, eb, gate, perm, counts, out);
}